// Round 12
// baseline (463.351 us; speedup 1.0000x reference)
//
#include <hip/hip_runtime.h>
#include <hip/hip_fp16.h>
#include <math.h>

#define NN 50000
#define NE 100000
#define FN 128
#define FE 16
#define HD 64
#define OUTD 32
#define NG 64
#define ZK 65           // 64 edge-MLP features + 1 bias slot (z=1)
#define EB 256          // edges per k_message block
#define NBMSG ((NE + EB - 1) / EB)

typedef unsigned int uint;
typedef unsigned short ushort;
typedef __attribute__((ext_vector_type(8))) short short8;
typedef __attribute__((ext_vector_type(8))) _Float16 half8;
typedef __attribute__((ext_vector_type(2))) _Float16 half2v;
typedef __attribute__((ext_vector_type(16))) float f32x16;

static __device__ __forceinline__ ushort f2h(float f) {
    _Float16 h = (_Float16)f;
    return __builtin_bit_cast(ushort, h);
}
static __device__ __forceinline__ float h2f(ushort u) {
    return (float)__builtin_bit_cast(_Float16, u);
}
// v_cvt_pkrtz_f16_f32: one inst packs 2 floats -> 2 fp16 in a uint
static __device__ __forceinline__ uint pkh2(float a, float b) {
    auto r = __builtin_amdgcn_cvt_pkrtz(a, b);
    return __builtin_bit_cast(uint, r);
}
// v_pk_mul_f16: packed fp16 multiply, result is already an A-fragment word
static __device__ __forceinline__ uint hmul2u(uint a, uint b) {
    half2v x = __builtin_bit_cast(half2v, a);
    half2v y = __builtin_bit_cast(half2v, b);
    half2v r = x * y;
    return __builtin_bit_cast(uint, r);
}
static __device__ __forceinline__ half8 u4h8(uint4 u) {
    return __builtin_bit_cast(half8, u);
}
static __device__ __forceinline__ float fsigmoid(float x) {
    return 1.f / (1.f + __expf(-x));
}
static __device__ __forceinline__ float ftanh(float x) {
    float t = __expf(2.f * x);
    return 1.f - 2.f / (t + 1.f);
}

// ---- prep ----
// Wtb: message B, CONTIGUOUS layout [slab][jb(8)][i(64)][hh(8)] (j = jb*8+hh).
//      Staging is a linear identity copy; ds_read_b128 is 16B/lane contiguous.
//      Fragment[hh] = W2[slab][i][jb*8+hh] = B[k=jb*8+hh][n=i].
// Bg2: GRU B, fragment layout [g(4)][ihr(2)][ks(8)][lhi(2)][l31(32)][hh(8)]:
//      value = gate-g weight [i = ihr*32+l31][k = ks*16+lhi*8+hh].
//      GATE STRIDE = 2*8*2*32*8 = 8192 ushorts. Read straight from L2 by k_gru
//      (contiguous 1KB per wave instruction; Bg2 = 64KB, L2-resident).
// Wet: Wenc^T for the encoder.
#define PREP_S0 (ZK * 4096)
#define PREP_S1 (256 * 128)
#define PREP_S2 (64 * 128)
__global__ void k_prep(const float* __restrict__ W_e2, const float* __restrict__ b_e2,
                       const float* __restrict__ W_ih, const float* __restrict__ W_hh,
                       const float* __restrict__ W_enc,
                       ushort* __restrict__ Wtb, ushort* __restrict__ Bg,
                       ushort* __restrict__ Wet) {
    int idx = blockIdx.x * 256 + threadIdx.x;
    if (idx < PREP_S0) {
        int k0 = idx >> 12, r = idx & 4095;
        int jb = r >> 9, rem = r & 511;
        int i = rem >> 3, hh = rem & 7;
        int j = jb * 8 + hh;
        float v = (k0 < 64) ? W_e2[k0 * 4096 + i * 64 + j] : b_e2[i * 64 + j];
        Wtb[idx] = f2h(v);
        return;
    }
    idx -= PREP_S0;
    if (idx < PREP_S1) {
        int hh = idx & 7;
        int l31 = (idx >> 3) & 31;
        int lhi = (idx >> 8) & 1;
        int ks  = (idx >> 9) & 7;
        int ihr = (idx >> 12) & 1;
        int g   = (idx >> 13) & 3;
        int i = ihr * 32 + l31;
        int k = ks * 16 + lhi * 8 + hh;
        float v = 0.f;
        if (g == 0)      v = (k < 64) ? W_ih[i * 64 + k]         : W_hh[i * 64 + (k - 64)];
        else if (g == 1) v = (k < 64) ? W_ih[(64 + i) * 64 + k]  : W_hh[(64 + i) * 64 + (k - 64)];
        else if (g == 2) v = (k < 64) ? W_ih[(128 + i) * 64 + k] : 0.f;
        else             v = (k < 64) ? 0.f                      : W_hh[(128 + i) * 64 + (k - 64)];
        Bg[idx] = f2h(v);
        return;
    }
    idx -= PREP_S1;
    if (idx < PREP_S2) {
        int n = idx >> 7, k = idx & 127;        // Wet[n][k] = W_enc[k][n]
        Wet[idx] = f2h(W_enc[k * 64 + n]);
    }
}

// ---- merged encoder + edge-MLP (grid split on blockIdx.x) ----
#define NBENC ((NN + 127) / 128)
#define NBEDG ((NE + 255) / 256)
__global__ __launch_bounds__(256, 2)
void k_enc_edge(const float* __restrict__ x, const ushort* __restrict__ Wet,
                const float* __restrict__ b_enc,
                const float* __restrict__ ea, const float* __restrict__ W_e1,
                const float* __restrict__ b_e1,
                ushort* __restrict__ hb,
                ushort* __restrict__ zbT, float* __restrict__ magg) {
    int t = threadIdx.x;
    if (blockIdx.x < NBENC) {
        __shared__ __align__(16) ushort blds[64 * 128];   // 16 KB, XOR-swizzled slots
        int wave = t >> 6, lane = t & 63, l31 = lane & 31, lhi = lane >> 5;
        #pragma unroll
        for (int call = 0; call < 4; call++) {            // 1024 slots of 16B, async
            int slot = call * 256 + t;
            int n = slot >> 4, p = slot & 15;
            int ssrc = p ^ (n & 15);
            const ushort* src = Wet + n * 128 + ssrc * 8;
            __builtin_amdgcn_global_load_lds(
                (const __attribute__((address_space(1))) void*)src,
                (__attribute__((address_space(3))) void*)&blds[(size_t)slot * 8],
                16, 0, 0);
        }
        int node0 = blockIdx.x * 128 + wave * 32;
        int m = node0 + l31;
        int mc = (m < NN) ? m : NN - 1;
        uint4 afr[8];
        const float* xr = x + (size_t)mc * 128;
        #pragma unroll
        for (int ks = 0; ks < 8; ks++) {
            float4 v0 = *(const float4*)(xr + ks * 16 + lhi * 8);
            float4 v1 = *(const float4*)(xr + ks * 16 + lhi * 8 + 4);
            uint4 u;
            u.x = pkh2(v0.x, v0.y); u.y = pkh2(v0.z, v0.w);
            u.z = pkh2(v1.x, v1.y); u.w = pkh2(v1.z, v1.w);
            afr[ks] = u;
        }
        __syncthreads();
        #pragma unroll
        for (int ct = 0; ct < 2; ct++) {
            f32x16 acc = {0};
            int n = ct * 32 + l31;
            #pragma unroll
            for (int ks = 0; ks < 8; ks++) {
                int sp = (ks * 2 + lhi) ^ (n & 15);
                short8 bf = *(const short8*)&blds[n * 128 + sp * 8];
                acc = __builtin_amdgcn_mfma_f32_32x32x16_f16(
                    u4h8(afr[ks]), __builtin_bit_cast(half8, bf), acc, 0, 0, 0);
            }
            int o = ct * 32 + l31;
            float bias = b_enc[o];
            #pragma unroll
            for (int r = 0; r < 16; r++) {
                int row = (r & 3) + 8 * (r >> 2) + 4 * lhi;
                int node = node0 + row;
                if (node < NN) {
                    float v = acc[r] + bias;
                    hb[node * 64 + o] = f2h(v);
                    magg[node * 64 + o] = 0.f;
                }
            }
        }
    } else {
        __shared__ float Ws[16 * 64];
        __shared__ float b1s[64];
        for (int idx = t; idx < 1024; idx += 256) Ws[idx] = W_e1[idx];
        if (t < 64) b1s[t] = b_e1[t];
        __syncthreads();
        int e = (blockIdx.x - NBENC) * 256 + t;
        int ec = (e < NE) ? e : NE - 1;
        float eav[16];
        const float4* ep = (const float4*)(ea + ec * 16);
        #pragma unroll
        for (int q = 0; q < 4; q++) {
            float4 v = ep[q];
            eav[q * 4 + 0] = v.x; eav[q * 4 + 1] = v.y; eav[q * 4 + 2] = v.z; eav[q * 4 + 3] = v.w;
        }
        if (e >= NE) return;
        #pragma unroll 4
        for (int k = 0; k < 64; k++) {
            float acc = b1s[k];
            #pragma unroll
            for (int f = 0; f < 16; f++) acc += eav[f] * Ws[f * 64 + k];
            zbT[(size_t)k * NE + e] = f2h(fmaxf(acc, 0.f));
        }
        // bias row (k0=64) is z==1.0 constant: handled in registers by k_message.
    }
}

// ---- MFMA message kernel: R8 structure, z via one-round-ahead REG prefetch ----
// Change vs R8 (proven, 73us): the 32KB z LDS tile is gone. Each wave prefetches
// next round's 4 z scalars (2 per k0) into registers DURING the current round;
// the top-of-round __syncthreads' vmcnt(0) drain (which we already pay for the
// W staging) guarantees they have landed -- zero new sync semantics, zero stall.
// LDS 66.5KB -> 34KB: capacity 4 blocks/CU, grid 391 fully co-resident in ONE
// phase (R8 ran two phases at 76% avg utilization); cross-block wave overlap
// hides the per-round barrier drain.
__global__ __launch_bounds__(256, 4)
void k_message(const ushort* __restrict__ zbT, const ushort* __restrict__ hb,
               const int* __restrict__ eidx, const ushort* __restrict__ Wtb,
               float* __restrict__ m_agg) {
    __shared__ __align__(16) ushort wlds[2][2 * 4096];   // 2 bufs x 2 slabs (16KB each)
    __shared__ int sdst[256];

    int t = threadIdx.x;
    int wave = t >> 6, lane = t & 63;
    int l31 = lane & 31, lhi = lane >> 5;
    int eblk = blockIdx.x * EB;
    int e0 = eblk + wave * 64;

    {
        int e = eblk + t; if (e >= NE) e = NE - 1;
        sdst[t] = eidx[NE + e];
    }

    // gather h rows as packed fp16 words -- latency hides under staging
    uint hw[2][16];
    #pragma unroll
    for (int mt = 0; mt < 2; mt++) {
        int e = e0 + mt * 32 + l31;
        int ec = (e < NE) ? e : NE - 1;
        int s = eidx[ec];
        const ushort* hrow = hb + (size_t)s * 64;
        #pragma unroll
        for (int c = 0; c < 4; c++) {
            uint4 v = *(const uint4*)(hrow + c * 16 + lhi * 8);
            hw[mt][c * 4 + 0] = v.x; hw[mt][c * 4 + 1] = v.y;
            hw[mt][c * 4 + 2] = v.z; hw[mt][c * 4 + 3] = v.w;
        }
    }

    // z prologue: rounds read past NE spill into the next zbT row (row 64 is the
    // guard); garbage lanes are masked by the e<NE guard at the atomics.
    const ushort* zb0 = zbT + e0;
    uint zc0 = zb0[l31],      zc1 = zb0[32 + l31];        // k0 = 0
    uint zc2 = zb0[NE + l31], zc3 = zb0[NE + 32 + l31];   // k0 = 1

    // W slab staging: one buffer = 2 slabs = 1024 slots of 16B (4 calls),
    // LINEAR identity copy (Wtb already in read order)
    auto stagew = [&](int slab0, int buf) {
        #pragma unroll
        for (int call = 0; call < 4; call++) {
            int slot = call * 256 + t;
            int slab = slab0 + (slot >> 9);
            if (slab > 64) slab = 64;                 // clamp (last round: 1 real slab)
            int wofs = slot & 511;
            const ushort* src = Wtb + (size_t)slab * 4096 + wofs * 8;
            __builtin_amdgcn_global_load_lds(
                (const __attribute__((address_space(1))) void*)src,
                (__attribute__((address_space(3))) void*)&wlds[buf][(size_t)slot * 8],
                16, 0, 0);
        }
    };
    stagew(0, 0);

    f32x16 acc00 = {0}, acc01 = {0}, acc10 = {0}, acc11 = {0};

    for (int rnd = 0; rnd < 33; rnd++) {
        __syncthreads();                              // buf rnd&1 + this round's z regs ready
        int buf = rnd & 1;
        if (rnd < 32) stagew(2 * rnd + 2, buf ^ 1);   // hides under this round's compute
        uint zn0 = 0, zn1 = 0, zn2 = 0, zn3 = 0;      // prefetch next round's z
        if (rnd < 31) {
            const ushort* zr2 = zbT + (size_t)(2 * rnd + 2) * NE + e0;
            const ushort* zr3 = zbT + (size_t)(2 * rnd + 3) * NE + e0;
            zn0 = zr2[l31]; zn1 = zr2[32 + l31];
            zn2 = zr3[l31]; zn3 = zr3[32 + l31];
        }
        int nk = (rnd < 32) ? 2 : 1;
        for (int kk = 0; kk < nk; kk++) {
            int k0 = 2 * rnd + kk;
            uint zz0, zz1;
            if (k0 < 64) {
                uint za = kk ? zc2 : zc0;
                uint zb = kk ? zc3 : zc1;
                zz0 = za | (za << 16);
                zz1 = zb | (zb << 16);
            } else {
                zz0 = 0x3C003C00u; zz1 = 0x3C003C00u; // bias slab: z == 1.0 (fp16)
            }
            const ushort* wb = &wlds[buf][kk * 4096];
            #pragma unroll
            for (int c = 0; c < 4; c++) {
                int jb = c * 2 + lhi;
                // contiguous 16B/lane reads: [jb][i][hh] layout, conflict-free
                short8 b0r = *(const short8*)&wb[jb * 512 + l31 * 8];
                short8 b1r = *(const short8*)&wb[jb * 512 + 256 + l31 * 8];
                uint4 au0, au1;
                au0.x = hmul2u(zz0, hw[0][c * 4 + 0]); au0.y = hmul2u(zz0, hw[0][c * 4 + 1]);
                au0.z = hmul2u(zz0, hw[0][c * 4 + 2]); au0.w = hmul2u(zz0, hw[0][c * 4 + 3]);
                au1.x = hmul2u(zz1, hw[1][c * 4 + 0]); au1.y = hmul2u(zz1, hw[1][c * 4 + 1]);
                au1.z = hmul2u(zz1, hw[1][c * 4 + 2]); au1.w = hmul2u(zz1, hw[1][c * 4 + 3]);
                half8 a0 = u4h8(au0), a1 = u4h8(au1);
                half8 b0 = __builtin_bit_cast(half8, b0r);
                half8 b1 = __builtin_bit_cast(half8, b1r);
                acc00 = __builtin_amdgcn_mfma_f32_32x32x16_f16(a0, b0, acc00, 0, 0, 0);
                acc01 = __builtin_amdgcn_mfma_f32_32x32x16_f16(a0, b1, acc01, 0, 0, 0);
                acc10 = __builtin_amdgcn_mfma_f32_32x32x16_f16(a1, b0, acc10, 0, 0, 0);
                acc11 = __builtin_amdgcn_mfma_f32_32x32x16_f16(a1, b1, acc11, 0, 0, 0);
            }
        }
        zc0 = zn0; zc1 = zn1; zc2 = zn2; zc3 = zn3;
    }

    // epilogue: D row = (r&3)+8*(r>>2)+4*lhi (edge-local), col = i (coalesced).
    #pragma unroll
    for (int r = 0; r < 16; r++) {
        int roff = (r & 3) + 8 * (r >> 2) + 4 * lhi;
        int eA = e0 + roff, eB = e0 + 32 + roff;
        if (eA < NE) {
            int d0 = sdst[wave * 64 + roff];
            atomicAdd(m_agg + (size_t)d0 * 64 + l31,      acc00[r]);
            atomicAdd(m_agg + (size_t)d0 * 64 + 32 + l31, acc01[r]);
        }
        if (eB < NE) {
            int d1 = sdst[wave * 64 + 32 + roff];
            atomicAdd(m_agg + (size_t)d1 * 64 + l31,      acc10[r]);
            atomicAdd(m_agg + (size_t)d1 * 64 + 32 + l31, acc11[r]);
        }
    }
}

// ---- MFMA GRU, LDS-free: B fragments straight from L2 (Bg2 fragment layout) ----
// 64 nodes/block, grid 782 (~3 blocks/CU, 12 waves/CU). Wave w: node-half
// nh=w>>1, i-half ih=w&1; 4 gate accs. Gate stride in Bg2 = 8192 ushorts.
// No staging barrier; one syncthreads only to order magg reads before re-zero.
#define NBGRU ((NN + 63) / 64)
__global__ __launch_bounds__(256, 3)
void k_gru(float* __restrict__ magg,
           const ushort* __restrict__ hb, const ushort* __restrict__ Bg2,
           const float* __restrict__ b_ih, const float* __restrict__ b_hh,
           ushort* __restrict__ hb_out, int zero_m) {
    int t = threadIdx.x;
    int w = t >> 6, lane = t & 63, l31 = lane & 31, lhi = lane >> 5;
    int nh = w >> 1, ih = w & 1;
    int node0 = blockIdx.x * 64 + nh * 32;
    int m = node0 + l31;
    int mc = (m < NN) ? m : NN - 1;
    uint4 afr[8];
    const float* mrow = magg + (size_t)mc * 64;
    #pragma unroll
    for (int ks = 0; ks < 4; ks++) {
        float4 v0 = *(const float4*)(mrow + ks * 16 + lhi * 8);
        float4 v1 = *(const float4*)(mrow + ks * 16 + lhi * 8 + 4);
        uint4 u;
        u.x = pkh2(v0.x, v0.y); u.y = pkh2(v0.z, v0.w);
        u.z = pkh2(v1.x, v1.y); u.w = pkh2(v1.z, v1.w);
        afr[ks] = u;
    }
    const ushort* hrow = hb + (size_t)mc * 64;
    #pragma unroll
    for (int ks = 4; ks < 8; ks++) {
        afr[ks] = *(const uint4*)(hrow + (ks - 4) * 16 + lhi * 8);
    }
    __syncthreads();                                  // all waves' magg reads done
    if (zero_m && ih == 0) {                          // zero for next step's atomics
        float4 zz = {0.f, 0.f, 0.f, 0.f};
        float* mw = magg + (size_t)mc * 64;
        #pragma unroll
        for (int ks = 0; ks < 4; ks++) {
            *(float4*)(mw + ks * 16 + lhi * 8) = zz;
            *(float4*)(mw + ks * 16 + lhi * 8 + 4) = zz;
        }
    }
    f32x16 aR = {0}, aZ = {0}, aI = {0}, aH = {0};
    #pragma unroll
    for (int ks = 0; ks < 8; ks++) {
        half8 a = u4h8(afr[ks]);
        // Bg2 offset: (((g*2+ih)*8+ks)*2+lhi)*256 + l31*8 -- coalesced 1KB/instr
        size_t ofs = (size_t)((ih * 8 + ks) * 2 + lhi) * 256 + l31 * 8;
        short8 bR = *(const short8*)&Bg2[ofs];
        short8 bZ = *(const short8*)&Bg2[ofs + 32 * 256];   // +8192  (gate stride)
        short8 bI = *(const short8*)&Bg2[ofs + 64 * 256];   // +16384
        short8 bH = *(const short8*)&Bg2[ofs + 96 * 256];   // +24576
        aR = __builtin_amdgcn_mfma_f32_32x32x16_f16(a, __builtin_bit_cast(half8, bR), aR, 0, 0, 0);
        aZ = __builtin_amdgcn_mfma_f32_32x32x16_f16(a, __builtin_bit_cast(half8, bZ), aZ, 0, 0, 0);
        aI = __builtin_amdgcn_mfma_f32_32x32x16_f16(a, __builtin_bit_cast(half8, bI), aI, 0, 0, 0);
        aH = __builtin_amdgcn_mfma_f32_32x32x16_f16(a, __builtin_bit_cast(half8, bH), aH, 0, 0, 0);
    }
    int i = ih * 32 + l31;
    float brv = b_ih[i] + b_hh[i];
    float bzv = b_ih[64 + i] + b_hh[64 + i];
    float biv = b_ih[128 + i];
    float bhv = b_hh[128 + i];
    #pragma unroll
    for (int r = 0; r < 16; r++) {
        int row = (r & 3) + 8 * (r >> 2) + 4 * lhi;
        int node = node0 + row;
        if (node < NN) {
            float ho = h2f(hb[node * 64 + i]);
            float rg = fsigmoid(aR[r] + brv);
            float zg = fsigmoid(aZ[r] + bzv);
            float ng = ftanh(aI[r] + biv + rg * (aH[r] + bhv));
            float hv = (1.f - zg) * ng + zg * ho;
            hb_out[node * 64 + i] = f2h(hv);
        }
    }
}

// ---- readout scatter: batch sorted -> run-length accumulate (fp16 state in) ----
__global__ __launch_bounds__(256)
void k_scatter_g(const ushort* __restrict__ hb, const int* __restrict__ batch,
                 float* __restrict__ g) {
    int t = threadIdx.x;
    int i = t & 63, sub = t >> 6;
    int n0 = blockIdx.x * 64 + sub * 16;
    if (n0 >= NN) return;
    float acc = 0.f;
    int curg = batch[n0];
    for (int q = 0; q < 16; q++) {
        int n = n0 + q;
        if (n >= NN) break;
        int gq = batch[n];                 // wave-uniform
        if (gq != curg) {
            atomicAdd(&g[curg * 64 + i], acc);
            acc = 0.f; curg = gq;
        }
        acc += h2f(hb[n * 64 + i]);
    }
    atomicAdd(&g[curg * 64 + i], acc);
}

__global__ __launch_bounds__(1024)
void k_readout(const float* __restrict__ g, const float* __restrict__ W1, const float* __restrict__ b1,
               const float* __restrict__ W2, const float* __restrict__ b2, float* __restrict__ out) {
    __shared__ float gs[64 * 64];
    __shared__ float ts[64 * 64];
    int t = threadIdx.x;
    for (int idx = t; idx < 4096; idx += 1024) gs[idx] = g[idx];
    __syncthreads();
    for (int idx = t; idx < 4096; idx += 1024) {
        int r = idx >> 6, c = idx & 63;
        float acc = b1[c];
        #pragma unroll 8
        for (int k = 0; k < 64; k++) acc += gs[r * 64 + k] * W1[k * 64 + c];
        ts[idx] = fmaxf(acc, 0.f);
    }
    __syncthreads();
    for (int idx = t; idx < 2048; idx += 1024) {
        int r = idx >> 5, c = idx & 31;
        float acc = b2[c];
        #pragma unroll 8
        for (int k = 0; k < 64; k++) acc += ts[r * 64 + k] * W2[k * 32 + c];
        out[idx] = acc;
    }
}

extern "C" void kernel_launch(void* const* d_in, const int* in_sizes, int n_in,
                              void* d_out, int out_size, void* d_ws, size_t ws_size,
                              hipStream_t stream) {
    const float* x     = (const float*)d_in[0];
    const int*   ei    = (const int*)  d_in[1];
    const float* ea    = (const float*)d_in[2];
    const int*   batch = (const int*)  d_in[3];
    const float* W_enc = (const float*)d_in[4];
    const float* b_enc = (const float*)d_in[5];
    const float* W_e1  = (const float*)d_in[6];
    const float* b_e1  = (const float*)d_in[7];
    const float* W_e2  = (const float*)d_in[8];
    const float* b_e2  = (const float*)d_in[9];
    const float* W_ih  = (const float*)d_in[10];
    const float* W_hh  = (const float*)d_in[11];
    const float* b_ih  = (const float*)d_in[12];
    const float* b_hh  = (const float*)d_in[13];
    const float* W_r1  = (const float*)d_in[14];
    const float* b_r1  = (const float*)d_in[15];
    const float* W_r2  = (const float*)d_in[16];
    const float* b_r2  = (const float*)d_in[17];
    float* out = (float*)d_out;

    float* ws    = (float*)d_ws;
    float* magg  = ws;                        // NN*64 fp32
    float* g     = magg + NN * 64;            // NG*64 fp32
    ushort* hb   = (ushort*)(g + NG * 64);    // NN*64 fp16
    ushort* hb2  = hb   + NN * 64;            // NN*64 fp16
    ushort* zbT  = hb2  + NN * 64;            // 65*NE fp16 (row 64 = read-guard only)
    ushort* Wtb  = zbT  + (size_t)ZK * NE;    // 65*4096 fp16 (contiguous slabs)
    ushort* Bgru = Wtb  + ZK * 4096;          // 256*128 fp16 (Bg2 fragment layout)
    ushort* Wet  = Bgru + 256 * 128;          // 64*128 fp16 (Wenc^T)

    hipLaunchKernelGGL(k_prep, dim3((PREP_S0 + PREP_S1 + PREP_S2 + 255) / 256), dim3(256), 0, stream,
                       W_e2, b_e2, W_ih, W_hh, W_enc, Wtb, Bgru, Wet);
    hipLaunchKernelGGL(k_enc_edge, dim3(NBENC + NBEDG), dim3(256), 0, stream,
                       x, Wet, b_enc, ea, W_e1, b_e1, hb, zbT, magg);

    ushort* hbc = hb; ushort* hbn = hb2;
    for (int s = 0; s < 3; s++) {
        hipLaunchKernelGGL(k_message, dim3(NBMSG), dim3(256), 0, stream,
                           zbT, hbc, ei, Wtb, magg);
        hipLaunchKernelGGL(k_gru,     dim3(NBGRU), dim3(256), 0, stream,
                           magg, hbc, Bgru, b_ih, b_hh, hbn, (s < 2) ? 1 : 0);
        ushort* tb = hbc; hbc = hbn; hbn = tb;
    }

    hipMemsetAsync(g, 0, (size_t)NG * 64 * sizeof(float), stream);
    hipLaunchKernelGGL(k_scatter_g, dim3((NN + 63) / 64), dim3(256), 0, stream, hbc, batch, g);
    hipLaunchKernelGGL(k_readout,   dim3(1), dim3(1024), 0, stream, g, W_r1, b_r1, W_r2, b_r2, out);
}

// Round 13
// 396.848 us; speedup vs baseline: 1.1676x; 1.1676x over previous
//
#include <hip/hip_runtime.h>
#include <hip/hip_fp16.h>
#include <math.h>

#define NN 50000
#define NE 100000
#define FN 128
#define FE 16
#define HD 64
#define OUTD 32
#define NG 64
#define ZK 65           // 64 edge-MLP features + 1 bias slot (z=1)
#define EB 256          // edges per k_message block
#define NBMSG ((NE + EB - 1) / EB)

typedef unsigned int uint;
typedef unsigned short ushort;
typedef __attribute__((ext_vector_type(8))) short short8;
typedef __attribute__((ext_vector_type(8))) _Float16 half8;
typedef __attribute__((ext_vector_type(2))) _Float16 half2v;
typedef __attribute__((ext_vector_type(16))) float f32x16;

static __device__ __forceinline__ ushort f2h(float f) {
    _Float16 h = (_Float16)f;
    return __builtin_bit_cast(ushort, h);
}
static __device__ __forceinline__ float h2f(ushort u) {
    return (float)__builtin_bit_cast(_Float16, u);
}
// v_cvt_pkrtz_f16_f32: one inst packs 2 floats -> 2 fp16 in a uint
static __device__ __forceinline__ uint pkh2(float a, float b) {
    auto r = __builtin_amdgcn_cvt_pkrtz(a, b);
    return __builtin_bit_cast(uint, r);
}
// v_pk_mul_f16: packed fp16 multiply, result is already an A-fragment word
static __device__ __forceinline__ uint hmul2u(uint a, uint b) {
    half2v x = __builtin_bit_cast(half2v, a);
    half2v y = __builtin_bit_cast(half2v, b);
    half2v r = x * y;
    return __builtin_bit_cast(uint, r);
}
static __device__ __forceinline__ half8 u4h8(uint4 u) {
    return __builtin_bit_cast(half8, u);
}
static __device__ __forceinline__ float fsigmoid(float x) {
    return 1.f / (1.f + __expf(-x));
}
static __device__ __forceinline__ float ftanh(float x) {
    float t = __expf(2.f * x);
    return 1.f - 2.f / (t + 1.f);
}

// ---- prep ----
// Wtb: message B, CONTIGUOUS layout [slab][jb(8)][i(64)][hh(8)] (j = jb*8+hh).
//      Staging is a linear identity copy; ds_read_b128 is 16B/lane contiguous.
//      Fragment[hh] = W2[slab][i][jb*8+hh] = B[k=jb*8+hh][n=i].
// Bgru: R5 layout [n(256)][k(128)], n = g*64+i -- LDS-staged k_gru (proven).
// Wet: Wenc^T for the encoder.
#define PREP_S0 (ZK * 4096)
#define PREP_S1 (256 * 128)
#define PREP_S2 (64 * 128)
__global__ void k_prep(const float* __restrict__ W_e2, const float* __restrict__ b_e2,
                       const float* __restrict__ W_ih, const float* __restrict__ W_hh,
                       const float* __restrict__ W_enc,
                       ushort* __restrict__ Wtb, ushort* __restrict__ Bg,
                       ushort* __restrict__ Wet) {
    int idx = blockIdx.x * 256 + threadIdx.x;
    if (idx < PREP_S0) {
        int k0 = idx >> 12, r = idx & 4095;
        int jb = r >> 9, rem = r & 511;
        int i = rem >> 3, hh = rem & 7;
        int j = jb * 8 + hh;
        float v = (k0 < 64) ? W_e2[k0 * 4096 + i * 64 + j] : b_e2[i * 64 + j];
        Wtb[idx] = f2h(v);
        return;
    }
    idx -= PREP_S0;
    if (idx < PREP_S1) {
        int n = idx >> 7, k = idx & 127;
        int g = n >> 6, i = n & 63;
        float v = 0.f;
        if (g == 0)      v = (k < 64) ? W_ih[i * 64 + k]         : W_hh[i * 64 + (k - 64)];
        else if (g == 1) v = (k < 64) ? W_ih[(64 + i) * 64 + k]  : W_hh[(64 + i) * 64 + (k - 64)];
        else if (g == 2) v = (k < 64) ? W_ih[(128 + i) * 64 + k] : 0.f;
        else             v = (k < 64) ? 0.f                      : W_hh[(128 + i) * 64 + (k - 64)];
        Bg[idx] = f2h(v);
        return;
    }
    idx -= PREP_S1;
    if (idx < PREP_S2) {
        int n = idx >> 7, k = idx & 127;        // Wet[n][k] = W_enc[k][n]
        Wet[idx] = f2h(W_enc[k * 64 + n]);
    }
}

// ---- merged encoder + edge-MLP (grid split on blockIdx.x) ----
#define NBENC ((NN + 127) / 128)
#define NBEDG ((NE + 255) / 256)
__global__ __launch_bounds__(256, 2)
void k_enc_edge(const float* __restrict__ x, const ushort* __restrict__ Wet,
                const float* __restrict__ b_enc,
                const float* __restrict__ ea, const float* __restrict__ W_e1,
                const float* __restrict__ b_e1,
                ushort* __restrict__ hb,
                ushort* __restrict__ zbT, float* __restrict__ magg) {
    int t = threadIdx.x;
    if (blockIdx.x < NBENC) {
        __shared__ __align__(16) ushort blds[64 * 128];   // 16 KB, XOR-swizzled slots
        int wave = t >> 6, lane = t & 63, l31 = lane & 31, lhi = lane >> 5;
        #pragma unroll
        for (int call = 0; call < 4; call++) {            // 1024 slots of 16B, async
            int slot = call * 256 + t;
            int n = slot >> 4, p = slot & 15;
            int ssrc = p ^ (n & 15);
            const ushort* src = Wet + n * 128 + ssrc * 8;
            __builtin_amdgcn_global_load_lds(
                (const __attribute__((address_space(1))) void*)src,
                (__attribute__((address_space(3))) void*)&blds[(size_t)slot * 8],
                16, 0, 0);
        }
        int node0 = blockIdx.x * 128 + wave * 32;
        int m = node0 + l31;
        int mc = (m < NN) ? m : NN - 1;
        uint4 afr[8];
        const float* xr = x + (size_t)mc * 128;
        #pragma unroll
        for (int ks = 0; ks < 8; ks++) {
            float4 v0 = *(const float4*)(xr + ks * 16 + lhi * 8);
            float4 v1 = *(const float4*)(xr + ks * 16 + lhi * 8 + 4);
            uint4 u;
            u.x = pkh2(v0.x, v0.y); u.y = pkh2(v0.z, v0.w);
            u.z = pkh2(v1.x, v1.y); u.w = pkh2(v1.z, v1.w);
            afr[ks] = u;
        }
        __syncthreads();
        #pragma unroll
        for (int ct = 0; ct < 2; ct++) {
            f32x16 acc = {0};
            int n = ct * 32 + l31;
            #pragma unroll
            for (int ks = 0; ks < 8; ks++) {
                int sp = (ks * 2 + lhi) ^ (n & 15);
                short8 bf = *(const short8*)&blds[n * 128 + sp * 8];
                acc = __builtin_amdgcn_mfma_f32_32x32x16_f16(
                    u4h8(afr[ks]), __builtin_bit_cast(half8, bf), acc, 0, 0, 0);
            }
            int o = ct * 32 + l31;
            float bias = b_enc[o];
            #pragma unroll
            for (int r = 0; r < 16; r++) {
                int row = (r & 3) + 8 * (r >> 2) + 4 * lhi;
                int node = node0 + row;
                if (node < NN) {
                    float v = acc[r] + bias;
                    hb[node * 64 + o] = f2h(v);
                    magg[node * 64 + o] = 0.f;
                }
            }
        }
    } else {
        __shared__ float Ws[16 * 64];
        __shared__ float b1s[64];
        for (int idx = t; idx < 1024; idx += 256) Ws[idx] = W_e1[idx];
        if (t < 64) b1s[t] = b_e1[t];
        __syncthreads();
        int e = (blockIdx.x - NBENC) * 256 + t;
        int ec = (e < NE) ? e : NE - 1;
        float eav[16];
        const float4* ep = (const float4*)(ea + ec * 16);
        #pragma unroll
        for (int q = 0; q < 4; q++) {
            float4 v = ep[q];
            eav[q * 4 + 0] = v.x; eav[q * 4 + 1] = v.y; eav[q * 4 + 2] = v.z; eav[q * 4 + 3] = v.w;
        }
        if (e >= NE) return;
        #pragma unroll 4
        for (int k = 0; k < 64; k++) {
            float acc = b1s[k];
            #pragma unroll
            for (int f = 0; f < 16; f++) acc += eav[f] * Ws[f * 64 + k];
            zbT[(size_t)k * NE + e] = f2h(fmaxf(acc, 0.f));
        }
        // bias row (k0=64) is z==1.0 constant: handled in registers by k_message.
    }
}

// ---- MFMA message kernel: R8 structure, waves split to 32 edges each ----
// R8 insight correction (R12): all 391 blocks are ALWAYS co-resident; occupancy
// is GRID-limited at 1564 waves (6.1/CU) because each wave owned 64 edges.
// Splitting each R8 wave into two 32-edge waves (8 waves x 32 edges per block,
// 512 threads) doubles wave count to 3128 (12.2/CU, ~3/SIMD) with ZERO extra
// work per edge: same MFMA total, same A-build per edge, same staging. Only
// cost: B-fragments read 2x from LDS (~76k cyc/CU floor, under budget). More
// waves/SIMD hide the per-round barrier+drain that R8's 1.5 waves/SIMD could
// not (m114 co-scheduling). LDS 65.5KB -> 2 blocks/CU, all co-resident.
__global__ __launch_bounds__(512, 4)
void k_message(const ushort* __restrict__ zbT, const ushort* __restrict__ hb,
               const int* __restrict__ eidx, const ushort* __restrict__ Wtb,
               float* __restrict__ m_agg) {
    __shared__ __align__(16) ushort wlds[2][2 * 4096];   // 2 bufs x 2 slabs (16KB each)
    __shared__ __align__(16) ushort zlds[64 * 256];      // 32KB: [k0][edge_local]
    __shared__ int sdst[256];

    int t = threadIdx.x;
    int w = t >> 6, lane = t & 63;
    int l31 = lane & 31, lhi = lane >> 5;
    int eblk = blockIdx.x * EB;
    int ew = eblk + w * 32;                              // wave's 32 edges

    if (t < 256) {
        int e = eblk + t; if (e >= NE) e = NE - 1;
        sdst[t] = eidx[NE + e];
    }

    // gather h rows as packed fp16 words: lanes l and l+32 cover the same edge,
    // different 8-dim chunks (lhi) -- exactly the 32x32 MFMA A-fragment layout.
    uint hw[16];
    {
        int e = ew + l31;
        int ec = (e < NE) ? e : NE - 1;
        int s = eidx[ec];
        const ushort* hrow = hb + (size_t)s * 64;
        #pragma unroll
        for (int c = 0; c < 4; c++) {
            uint4 v = *(const uint4*)(hrow + c * 16 + lhi * 8);
            hw[c * 4 + 0] = v.x; hw[c * 4 + 1] = v.y;
            hw[c * 4 + 2] = v.z; hw[c * 4 + 3] = v.w;
        }
    }

    // stage z-tile: 64 rows x 512B = 2048 slots of 16B (4 calls over 512 thr)
    #pragma unroll
    for (int call = 0; call < 4; call++) {
        int slot = call * 512 + t;
        int k0 = slot >> 5, p = slot & 31;
        const ushort* src = zbT + (size_t)k0 * NE + eblk + p * 8;
        __builtin_amdgcn_global_load_lds(
            (const __attribute__((address_space(1))) void*)src,
            (__attribute__((address_space(3))) void*)&zlds[(size_t)slot * 8],
            16, 0, 0);
    }

    // W slab staging: one buffer = 2 slabs = 1024 slots of 16B (2 calls),
    // LINEAR identity copy (Wtb already in read order)
    auto stagew = [&](int slab0, int buf) {
        #pragma unroll
        for (int call = 0; call < 2; call++) {
            int slot = call * 512 + t;
            int slab = slab0 + (slot >> 9);
            if (slab > 64) slab = 64;                 // clamp (last round: 1 real slab)
            int wofs = slot & 511;
            const ushort* src = Wtb + (size_t)slab * 4096 + wofs * 8;
            __builtin_amdgcn_global_load_lds(
                (const __attribute__((address_space(1))) void*)src,
                (__attribute__((address_space(3))) void*)&wlds[buf][(size_t)slot * 8],
                16, 0, 0);
        }
    };
    stagew(0, 0);

    f32x16 acc0 = {0}, acc1 = {0};

    for (int rnd = 0; rnd < 33; rnd++) {
        __syncthreads();                              // buf rnd&1 + (rnd==0: z-tile) ready
        int buf = rnd & 1;
        if (rnd < 32) stagew(2 * rnd + 2, buf ^ 1);   // hides under this round's compute
        int nk = (rnd < 32) ? 2 : 1;
        for (int kk = 0; kk < nk; kk++) {
            int k0 = 2 * rnd + kk;
            uint zz;
            if (k0 < 64) {
                uint za = zlds[k0 * 256 + w * 32 + l31];   // lanes l, l+32: broadcast
                zz = za | (za << 16);
            } else {
                zz = 0x3C003C00u;                     // bias slab: z == 1.0 (fp16)
            }
            const ushort* wb = &wlds[buf][kk * 4096];
            #pragma unroll
            for (int c = 0; c < 4; c++) {
                int jb = c * 2 + lhi;
                // contiguous 16B/lane reads: [jb][i][hh] layout, conflict-free
                short8 b0r = *(const short8*)&wb[jb * 512 + l31 * 8];
                short8 b1r = *(const short8*)&wb[jb * 512 + 256 + l31 * 8];
                uint4 au;
                au.x = hmul2u(zz, hw[c * 4 + 0]); au.y = hmul2u(zz, hw[c * 4 + 1]);
                au.z = hmul2u(zz, hw[c * 4 + 2]); au.w = hmul2u(zz, hw[c * 4 + 3]);
                half8 a = u4h8(au);
                half8 b0 = __builtin_bit_cast(half8, b0r);
                half8 b1 = __builtin_bit_cast(half8, b1r);
                acc0 = __builtin_amdgcn_mfma_f32_32x32x16_f16(a, b0, acc0, 0, 0, 0);
                acc1 = __builtin_amdgcn_mfma_f32_32x32x16_f16(a, b1, acc1, 0, 0, 0);
            }
        }
    }

    // epilogue: D row = (r&3)+8*(r>>2)+4*lhi (edge-local), col = i (coalesced).
    // Guard e<NE: invalid-edge lanes carry garbage (z-tile tail reads past NE).
    #pragma unroll
    for (int r = 0; r < 16; r++) {
        int roff = (r & 3) + 8 * (r >> 2) + 4 * lhi;
        int e = ew + roff;
        if (e < NE) {
            int d = sdst[w * 32 + roff];
            atomicAdd(m_agg + (size_t)d * 64 + l31,      acc0[r]);
            atomicAdd(m_agg + (size_t)d * 64 + 32 + l31, acc1[r]);
        }
    }
}

// ---- MFMA GRU: [50000, 128]([m|h]) x [128, 256](r,z,in,hn) -- R5/R8-proven ----
__global__ __launch_bounds__(256, 2)
void k_gru(float* __restrict__ magg,
           const ushort* __restrict__ hb, const ushort* __restrict__ Bg,
           const float* __restrict__ b_ih, const float* __restrict__ b_hh,
           ushort* __restrict__ hb_out, int zero_m) {
    __shared__ __align__(16) ushort blds[256 * 128];  // 64 KB, XOR-swizzled slots
    int t = threadIdx.x;
    int wave = t >> 6, lane = t & 63, l31 = lane & 31, lhi = lane >> 5;
    #pragma unroll
    for (int call = 0; call < 16; call++) {           // 4096 slots of 16B, async
        int slot = call * 256 + t;
        int n = slot >> 4, p = slot & 15;
        int ssrc = p ^ (n & 15);
        const ushort* src = Bg + n * 128 + ssrc * 8;
        __builtin_amdgcn_global_load_lds(
            (const __attribute__((address_space(1))) void*)src,
            (__attribute__((address_space(3))) void*)&blds[(size_t)slot * 8],
            16, 0, 0);
    }
    int node0 = blockIdx.x * 128 + wave * 32;
    int m = node0 + l31;
    int mc = (m < NN) ? m : NN - 1;
    uint4 afr[8];
    const float* mrow = magg + (size_t)mc * 64;
    #pragma unroll
    for (int ks = 0; ks < 4; ks++) {
        float4 v0 = *(const float4*)(mrow + ks * 16 + lhi * 8);
        float4 v1 = *(const float4*)(mrow + ks * 16 + lhi * 8 + 4);
        uint4 u;
        u.x = pkh2(v0.x, v0.y); u.y = pkh2(v0.z, v0.w);
        u.z = pkh2(v1.x, v1.y); u.w = pkh2(v1.z, v1.w);
        afr[ks] = u;
    }
    const ushort* hrow = hb + (size_t)mc * 64;
    #pragma unroll
    for (int ks = 4; ks < 8; ks++) {
        afr[ks] = *(const uint4*)(hrow + (ks - 4) * 16 + lhi * 8);
    }
    __syncthreads();                                  // staging + magg reads drained
    if (zero_m) {                                     // zero for next step's atomics
        float4 zz = {0.f, 0.f, 0.f, 0.f};
        float* mw = magg + (size_t)mc * 64;
        #pragma unroll
        for (int ks = 0; ks < 4; ks++) {
            *(float4*)(mw + ks * 16 + lhi * 8) = zz;
            *(float4*)(mw + ks * 16 + lhi * 8 + 4) = zz;
        }
    }
    #pragma unroll
    for (int ct = 0; ct < 2; ct++) {
        f32x16 aR = {0}, aZ = {0}, aI = {0}, aH = {0};
        int nR = 0   + ct * 32 + l31;
        int nZ = 64  + ct * 32 + l31;
        int nI = 128 + ct * 32 + l31;
        int nH = 192 + ct * 32 + l31;
        #pragma unroll
        for (int ks = 0; ks < 8; ks++) {
            int s = ks * 2 + lhi;
            half8 a = u4h8(afr[ks]);
            short8 bR = *(const short8*)&blds[nR * 128 + (s ^ (nR & 15)) * 8];
            short8 bZ = *(const short8*)&blds[nZ * 128 + (s ^ (nZ & 15)) * 8];
            short8 bI = *(const short8*)&blds[nI * 128 + (s ^ (nI & 15)) * 8];
            short8 bH = *(const short8*)&blds[nH * 128 + (s ^ (nH & 15)) * 8];
            aR = __builtin_amdgcn_mfma_f32_32x32x16_f16(a, __builtin_bit_cast(half8, bR), aR, 0, 0, 0);
            aZ = __builtin_amdgcn_mfma_f32_32x32x16_f16(a, __builtin_bit_cast(half8, bZ), aZ, 0, 0, 0);
            aI = __builtin_amdgcn_mfma_f32_32x32x16_f16(a, __builtin_bit_cast(half8, bI), aI, 0, 0, 0);
            aH = __builtin_amdgcn_mfma_f32_32x32x16_f16(a, __builtin_bit_cast(half8, bH), aH, 0, 0, 0);
        }
        int i = ct * 32 + l31;
        float brv = b_ih[i] + b_hh[i];
        float bzv = b_ih[64 + i] + b_hh[64 + i];
        float biv = b_ih[128 + i];
        float bhv = b_hh[128 + i];
        #pragma unroll
        for (int r = 0; r < 16; r++) {
            int row = (r & 3) + 8 * (r >> 2) + 4 * lhi;
            int node = node0 + row;
            if (node < NN) {
                float ho = h2f(hb[node * 64 + i]);
                float rg = fsigmoid(aR[r] + brv);
                float zg = fsigmoid(aZ[r] + bzv);
                float ng = ftanh(aI[r] + biv + rg * (aH[r] + bhv));
                float hv = (1.f - zg) * ng + zg * ho;
                hb_out[node * 64 + i] = f2h(hv);
            }
        }
    }
}

// ---- readout scatter: batch sorted -> run-length accumulate (fp16 state in) ----
__global__ __launch_bounds__(256)
void k_scatter_g(const ushort* __restrict__ hb, const int* __restrict__ batch,
                 float* __restrict__ g) {
    int t = threadIdx.x;
    int i = t & 63, sub = t >> 6;
    int n0 = blockIdx.x * 64 + sub * 16;
    if (n0 >= NN) return;
    float acc = 0.f;
    int curg = batch[n0];
    for (int q = 0; q < 16; q++) {
        int n = n0 + q;
        if (n >= NN) break;
        int gq = batch[n];                 // wave-uniform
        if (gq != curg) {
            atomicAdd(&g[curg * 64 + i], acc);
            acc = 0.f; curg = gq;
        }
        acc += h2f(hb[n * 64 + i]);
    }
    atomicAdd(&g[curg * 64 + i], acc);
}

__global__ __launch_bounds__(1024)
void k_readout(const float* __restrict__ g, const float* __restrict__ W1, const float* __restrict__ b1,
               const float* __restrict__ W2, const float* __restrict__ b2, float* __restrict__ out) {
    __shared__ float gs[64 * 64];
    __shared__ float ts[64 * 64];
    int t = threadIdx.x;
    for (int idx = t; idx < 4096; idx += 1024) gs[idx] = g[idx];
    __syncthreads();
    for (int idx = t; idx < 4096; idx += 1024) {
        int r = idx >> 6, c = idx & 63;
        float acc = b1[c];
        #pragma unroll 8
        for (int k = 0; k < 64; k++) acc += gs[r * 64 + k] * W1[k * 64 + c];
        ts[idx] = fmaxf(acc, 0.f);
    }
    __syncthreads();
    for (int idx = t; idx < 2048; idx += 1024) {
        int r = idx >> 5, c = idx & 31;
        float acc = b2[c];
        #pragma unroll 8
        for (int k = 0; k < 64; k++) acc += ts[r * 64 + k] * W2[k * 32 + c];
        out[idx] = acc;
    }
}

extern "C" void kernel_launch(void* const* d_in, const int* in_sizes, int n_in,
                              void* d_out, int out_size, void* d_ws, size_t ws_size,
                              hipStream_t stream) {
    const float* x     = (const float*)d_in[0];
    const int*   ei    = (const int*)  d_in[1];
    const float* ea    = (const float*)d_in[2];
    const int*   batch = (const int*)  d_in[3];
    const float* W_enc = (const float*)d_in[4];
    const float* b_enc = (const float*)d_in[5];
    const float* W_e1  = (const float*)d_in[6];
    const float* b_e1  = (const float*)d_in[7];
    const float* W_e2  = (const float*)d_in[8];
    const float* b_e2  = (const float*)d_in[9];
    const float* W_ih  = (const float*)d_in[10];
    const float* W_hh  = (const float*)d_in[11];
    const float* b_ih  = (const float*)d_in[12];
    const float* b_hh  = (const float*)d_in[13];
    const float* W_r1  = (const float*)d_in[14];
    const float* b_r1  = (const float*)d_in[15];
    const float* W_r2  = (const float*)d_in[16];
    const float* b_r2  = (const float*)d_in[17];
    float* out = (float*)d_out;

    float* ws    = (float*)d_ws;
    float* magg  = ws;                        // NN*64 fp32
    float* g     = magg + NN * 64;            // NG*64 fp32
    ushort* hb   = (ushort*)(g + NG * 64);    // NN*64 fp16
    ushort* hb2  = hb   + NN * 64;            // NN*64 fp16
    ushort* zbT  = hb2  + NN * 64;            // 65*NE fp16 (row 64 = read-guard only)
    ushort* Wtb  = zbT  + (size_t)ZK * NE;    // 65*4096 fp16 (contiguous slabs)
    ushort* Bgru = Wtb  + ZK * 4096;          // 256*128 fp16 (R5 layout)
    ushort* Wet  = Bgru + 256 * 128;          // 64*128 fp16 (Wenc^T)

    hipLaunchKernelGGL(k_prep, dim3((PREP_S0 + PREP_S1 + PREP_S2 + 255) / 256), dim3(256), 0, stream,
                       W_e2, b_e2, W_ih, W_hh, W_enc, Wtb, Bgru, Wet);
    hipLaunchKernelGGL(k_enc_edge, dim3(NBENC + NBEDG), dim3(256), 0, stream,
                       x, Wet, b_enc, ea, W_e1, b_e1, hb, zbT, magg);

    ushort* hbc = hb; ushort* hbn = hb2;
    for (int s = 0; s < 3; s++) {
        hipLaunchKernelGGL(k_message, dim3(NBMSG), dim3(512), 0, stream,
                           zbT, hbc, ei, Wtb, magg);
        hipLaunchKernelGGL(k_gru,     dim3((NN + 127) / 128), dim3(256), 0, stream,
                           magg, hbc, Bgru, b_ih, b_hh, hbn, (s < 2) ? 1 : 0);
        ushort* tb = hbc; hbc = hbn; hbn = tb;
    }

    hipMemsetAsync(g, 0, (size_t)NG * 64 * sizeof(float), stream);
    hipLaunchKernelGGL(k_scatter_g, dim3((NN + 63) / 64), dim3(256), 0, stream, hbc, batch, g);
    hipLaunchKernelGGL(k_readout,   dim3(1), dim3(1024), 0, stream, g, W_r1, b_r1, W_r2, b_r2, out);
}

// Round 14
// 363.587 us; speedup vs baseline: 1.2744x; 1.0915x over previous
//
#include <hip/hip_runtime.h>
#include <hip/hip_fp16.h>
#include <math.h>

#define NN 50000
#define NE 100000
#define FN 128
#define FE 16
#define HD 64
#define OUTD 32
#define NG 64
#define ZK 65           // 64 edge-MLP features + 1 bias slot (z=1)
#define EB 256          // edges per k_message block
#define NBMSG ((NE + EB - 1) / EB)

typedef unsigned int uint;
typedef unsigned short ushort;
typedef __attribute__((ext_vector_type(8))) short short8;
typedef __attribute__((ext_vector_type(8))) _Float16 half8;
typedef __attribute__((ext_vector_type(2))) _Float16 half2v;
typedef __attribute__((ext_vector_type(16))) float f32x16;

static __device__ __forceinline__ ushort f2h(float f) {
    _Float16 h = (_Float16)f;
    return __builtin_bit_cast(ushort, h);
}
static __device__ __forceinline__ float h2f(ushort u) {
    return (float)__builtin_bit_cast(_Float16, u);
}
// v_cvt_pkrtz_f16_f32: one inst packs 2 floats -> 2 fp16 in a uint
static __device__ __forceinline__ uint pkh2(float a, float b) {
    auto r = __builtin_amdgcn_cvt_pkrtz(a, b);
    return __builtin_bit_cast(uint, r);
}
// v_pk_mul_f16: packed fp16 multiply, result is already an A-fragment word
static __device__ __forceinline__ uint hmul2u(uint a, uint b) {
    half2v x = __builtin_bit_cast(half2v, a);
    half2v y = __builtin_bit_cast(half2v, b);
    half2v r = x * y;
    return __builtin_bit_cast(uint, r);
}
static __device__ __forceinline__ half8 u4h8(uint4 u) {
    return __builtin_bit_cast(half8, u);
}
static __device__ __forceinline__ float fsigmoid(float x) {
    return 1.f / (1.f + __expf(-x));
}
static __device__ __forceinline__ float ftanh(float x) {
    float t = __expf(2.f * x);
    return 1.f - 2.f / (t + 1.f);
}

// ---- prep ----
// Wtb: message B, CONTIGUOUS layout [slab][jb(8)][i(64)][hh(8)] (j = jb*8+hh).
//      Staging is a linear identity copy; ds_read_b128 is 16B/lane contiguous.
//      Fragment[hh] = W2[slab][i][jb*8+hh] = B[k=jb*8+hh][n=i].
// Bgru: R5 layout [n(256)][k(128)], n = g*64+i -- LDS-staged k_gru (proven).
// Wet: Wenc^T for the encoder.
#define PREP_S0 (ZK * 4096)
#define PREP_S1 (256 * 128)
#define PREP_S2 (64 * 128)
__global__ void k_prep(const float* __restrict__ W_e2, const float* __restrict__ b_e2,
                       const float* __restrict__ W_ih, const float* __restrict__ W_hh,
                       const float* __restrict__ W_enc,
                       ushort* __restrict__ Wtb, ushort* __restrict__ Bg,
                       ushort* __restrict__ Wet) {
    int idx = blockIdx.x * 256 + threadIdx.x;
    if (idx < PREP_S0) {
        int k0 = idx >> 12, r = idx & 4095;
        int jb = r >> 9, rem = r & 511;
        int i = rem >> 3, hh = rem & 7;
        int j = jb * 8 + hh;
        float v = (k0 < 64) ? W_e2[k0 * 4096 + i * 64 + j] : b_e2[i * 64 + j];
        Wtb[idx] = f2h(v);
        return;
    }
    idx -= PREP_S0;
    if (idx < PREP_S1) {
        int n = idx >> 7, k = idx & 127;
        int g = n >> 6, i = n & 63;
        float v = 0.f;
        if (g == 0)      v = (k < 64) ? W_ih[i * 64 + k]         : W_hh[i * 64 + (k - 64)];
        else if (g == 1) v = (k < 64) ? W_ih[(64 + i) * 64 + k]  : W_hh[(64 + i) * 64 + (k - 64)];
        else if (g == 2) v = (k < 64) ? W_ih[(128 + i) * 64 + k] : 0.f;
        else             v = (k < 64) ? 0.f                      : W_hh[(128 + i) * 64 + (k - 64)];
        Bg[idx] = f2h(v);
        return;
    }
    idx -= PREP_S1;
    if (idx < PREP_S2) {
        int n = idx >> 7, k = idx & 127;        // Wet[n][k] = W_enc[k][n]
        Wet[idx] = f2h(W_enc[k * 64 + n]);
    }
}

// ---- merged encoder + edge-MLP (grid split on blockIdx.x) ----
#define NBENC ((NN + 127) / 128)
#define NBEDG ((NE + 255) / 256)
__global__ __launch_bounds__(256, 2)
void k_enc_edge(const float* __restrict__ x, const ushort* __restrict__ Wet,
                const float* __restrict__ b_enc,
                const float* __restrict__ ea, const float* __restrict__ W_e1,
                const float* __restrict__ b_e1,
                ushort* __restrict__ hb,
                ushort* __restrict__ zbT, ushort* __restrict__ magg) {
    int t = threadIdx.x;
    if (blockIdx.x < NBENC) {
        __shared__ __align__(16) ushort blds[64 * 128];   // 16 KB, XOR-swizzled slots
        int wave = t >> 6, lane = t & 63, l31 = lane & 31, lhi = lane >> 5;
        #pragma unroll
        for (int call = 0; call < 4; call++) {            // 1024 slots of 16B, async
            int slot = call * 256 + t;
            int n = slot >> 4, p = slot & 15;
            int ssrc = p ^ (n & 15);
            const ushort* src = Wet + n * 128 + ssrc * 8;
            __builtin_amdgcn_global_load_lds(
                (const __attribute__((address_space(1))) void*)src,
                (__attribute__((address_space(3))) void*)&blds[(size_t)slot * 8],
                16, 0, 0);
        }
        int node0 = blockIdx.x * 128 + wave * 32;
        int m = node0 + l31;
        int mc = (m < NN) ? m : NN - 1;
        uint4 afr[8];
        const float* xr = x + (size_t)mc * 128;
        #pragma unroll
        for (int ks = 0; ks < 8; ks++) {
            float4 v0 = *(const float4*)(xr + ks * 16 + lhi * 8);
            float4 v1 = *(const float4*)(xr + ks * 16 + lhi * 8 + 4);
            uint4 u;
            u.x = pkh2(v0.x, v0.y); u.y = pkh2(v0.z, v0.w);
            u.z = pkh2(v1.x, v1.y); u.w = pkh2(v1.z, v1.w);
            afr[ks] = u;
        }
        __syncthreads();
        #pragma unroll
        for (int ct = 0; ct < 2; ct++) {
            f32x16 acc = {0};
            int n = ct * 32 + l31;
            #pragma unroll
            for (int ks = 0; ks < 8; ks++) {
                int sp = (ks * 2 + lhi) ^ (n & 15);
                short8 bf = *(const short8*)&blds[n * 128 + sp * 8];
                acc = __builtin_amdgcn_mfma_f32_32x32x16_f16(
                    u4h8(afr[ks]), __builtin_bit_cast(half8, bf), acc, 0, 0, 0);
            }
            int o = ct * 32 + l31;
            float bias = b_enc[o];
            #pragma unroll
            for (int r = 0; r < 16; r++) {
                int row = (r & 3) + 8 * (r >> 2) + 4 * lhi;
                int node = node0 + row;
                if (node < NN) {
                    float v = acc[r] + bias;
                    hb[node * 64 + o] = f2h(v);
                    magg[node * 64 + o] = 0;            // fp16 zero
                }
            }
        }
    } else {
        __shared__ float Ws[16 * 64];
        __shared__ float b1s[64];
        for (int idx = t; idx < 1024; idx += 256) Ws[idx] = W_e1[idx];
        if (t < 64) b1s[t] = b_e1[t];
        __syncthreads();
        int e = (blockIdx.x - NBENC) * 256 + t;
        int ec = (e < NE) ? e : NE - 1;
        float eav[16];
        const float4* ep = (const float4*)(ea + ec * 16);
        #pragma unroll
        for (int q = 0; q < 4; q++) {
            float4 v = ep[q];
            eav[q * 4 + 0] = v.x; eav[q * 4 + 1] = v.y; eav[q * 4 + 2] = v.z; eav[q * 4 + 3] = v.w;
        }
        if (e >= NE) return;
        #pragma unroll 4
        for (int k = 0; k < 64; k++) {
            float acc = b1s[k];
            #pragma unroll
            for (int f = 0; f < 16; f++) acc += eav[f] * Ws[f * 64 + k];
            zbT[(size_t)k * NE + e] = f2h(fmaxf(acc, 0.f));
        }
        // bias row (k0=64) is z==1.0 constant: handled in registers by k_message.
    }
}

// ---- MFMA message kernel: R13 structure + PACKED-FP16 atomics ----
// R13's decisive datapoint: dur == hbm_bytes/~550 GB/s across every passing
// variant (R8 41MB/73us, R13 41/74, R12 51/94, R4 200MB/394us) -- the kernel
// is pinned to the atomic/streaming ceiling, dominated by the 25.6MB fp32
// atomic stream (6.4M ops, each 4B hits HBM per WRITE_SIZE). Fix: accumulate
// m_agg in fp16 with global_atomic_pk_add_f16: pair adjacent columns via one
// shfl_xor(1); even lanes carry acc0-pairs (cols l31,l31+1), odd lanes carry
// acc1-pairs (cols 32+l31-1,32+l31). Atomic ops 6.4M->3.2M, bytes 25.6->12.8MB.
// Precision: magg already enters the GRU through an fp16 cast; fp16 accum of
// ~2-6 messages adds ~5e-4 relative (absmax 0.125 vs threshold 1.1).
__global__ __launch_bounds__(512, 4)
void k_message(const ushort* __restrict__ zbT, const ushort* __restrict__ hb,
               const int* __restrict__ eidx, const ushort* __restrict__ Wtb,
               ushort* __restrict__ m_agg) {
    __shared__ __align__(16) ushort wlds[2][2 * 4096];   // 2 bufs x 2 slabs (16KB each)
    __shared__ __align__(16) ushort zlds[64 * 256];      // 32KB: [k0][edge_local]
    __shared__ int sdst[256];

    int t = threadIdx.x;
    int w = t >> 6, lane = t & 63;
    int l31 = lane & 31, lhi = lane >> 5;
    int eblk = blockIdx.x * EB;
    int ew = eblk + w * 32;                              // wave's 32 edges

    if (t < 256) {
        int e = eblk + t; if (e >= NE) e = NE - 1;
        sdst[t] = eidx[NE + e];
    }

    // gather h rows as packed fp16 words: lanes l and l+32 cover the same edge,
    // different 8-dim chunks (lhi) -- exactly the 32x32 MFMA A-fragment layout.
    uint hw[16];
    {
        int e = ew + l31;
        int ec = (e < NE) ? e : NE - 1;
        int s = eidx[ec];
        const ushort* hrow = hb + (size_t)s * 64;
        #pragma unroll
        for (int c = 0; c < 4; c++) {
            uint4 v = *(const uint4*)(hrow + c * 16 + lhi * 8);
            hw[c * 4 + 0] = v.x; hw[c * 4 + 1] = v.y;
            hw[c * 4 + 2] = v.z; hw[c * 4 + 3] = v.w;
        }
    }

    // stage z-tile: 64 rows x 512B = 2048 slots of 16B (4 calls over 512 thr)
    #pragma unroll
    for (int call = 0; call < 4; call++) {
        int slot = call * 512 + t;
        int k0 = slot >> 5, p = slot & 31;
        const ushort* src = zbT + (size_t)k0 * NE + eblk + p * 8;
        __builtin_amdgcn_global_load_lds(
            (const __attribute__((address_space(1))) void*)src,
            (__attribute__((address_space(3))) void*)&zlds[(size_t)slot * 8],
            16, 0, 0);
    }

    // W slab staging: one buffer = 2 slabs = 1024 slots of 16B (2 calls),
    // LINEAR identity copy (Wtb already in read order)
    auto stagew = [&](int slab0, int buf) {
        #pragma unroll
        for (int call = 0; call < 2; call++) {
            int slot = call * 512 + t;
            int slab = slab0 + (slot >> 9);
            if (slab > 64) slab = 64;                 // clamp (last round: 1 real slab)
            int wofs = slot & 511;
            const ushort* src = Wtb + (size_t)slab * 4096 + wofs * 8;
            __builtin_amdgcn_global_load_lds(
                (const __attribute__((address_space(1))) void*)src,
                (__attribute__((address_space(3))) void*)&wlds[buf][(size_t)slot * 8],
                16, 0, 0);
        }
    };
    stagew(0, 0);

    f32x16 acc0 = {0}, acc1 = {0};

    for (int rnd = 0; rnd < 33; rnd++) {
        __syncthreads();                              // buf rnd&1 + (rnd==0: z-tile) ready
        int buf = rnd & 1;
        if (rnd < 32) stagew(2 * rnd + 2, buf ^ 1);   // hides under this round's compute
        int nk = (rnd < 32) ? 2 : 1;
        for (int kk = 0; kk < nk; kk++) {
            int k0 = 2 * rnd + kk;
            uint zz;
            if (k0 < 64) {
                uint za = zlds[k0 * 256 + w * 32 + l31];   // lanes l, l+32: broadcast
                zz = za | (za << 16);
            } else {
                zz = 0x3C003C00u;                     // bias slab: z == 1.0 (fp16)
            }
            const ushort* wb = &wlds[buf][kk * 4096];
            #pragma unroll
            for (int c = 0; c < 4; c++) {
                int jb = c * 2 + lhi;
                // contiguous 16B/lane reads: [jb][i][hh] layout, conflict-free
                short8 b0r = *(const short8*)&wb[jb * 512 + l31 * 8];
                short8 b1r = *(const short8*)&wb[jb * 512 + 256 + l31 * 8];
                uint4 au;
                au.x = hmul2u(zz, hw[c * 4 + 0]); au.y = hmul2u(zz, hw[c * 4 + 1]);
                au.z = hmul2u(zz, hw[c * 4 + 2]); au.w = hmul2u(zz, hw[c * 4 + 3]);
                half8 a = u4h8(au);
                half8 b0 = __builtin_bit_cast(half8, b0r);
                half8 b1 = __builtin_bit_cast(half8, b1r);
                acc0 = __builtin_amdgcn_mfma_f32_32x32x16_f16(a, b0, acc0, 0, 0, 0);
                acc1 = __builtin_amdgcn_mfma_f32_32x32x16_f16(a, b1, acc1, 0, 0, 0);
            }
        }
    }

    // epilogue: packed-fp16 atomics. Pair adjacent columns via shfl_xor(1);
    // lanes l,l^1 share the same edge (roff depends only on lhi). Even lane:
    // cols (l31, l31+1) from acc0; odd lane: cols (32+l31-1, 32+l31) from acc1.
    // One full 64-lane global_atomic_pk_add_f16 per r (16 total vs 32 fp32).
    #pragma unroll
    for (int r = 0; r < 16; r++) {
        int roff = (r & 3) + 8 * (r >> 2) + 4 * lhi;
        int e = ew + roff;
        float p0 = __shfl_xor(acc0[r], 1);
        float p1 = __shfl_xor(acc1[r], 1);
        if (e < NE) {
            int d = sdst[w * 32 + roff];
            uint pv  = (lane & 1) ? pkh2(p1, acc1[r]) : pkh2(acc0[r], p0);
            int col  = (lane & 1) ? (32 + (l31 & ~1)) : l31;
            unsafeAtomicAdd((__half2*)(m_agg + (size_t)d * 64 + col),
                            __builtin_bit_cast(__half2, pv));
        }
    }
}

// ---- MFMA GRU: [50000, 128]([m|h]) x [128, 256](r,z,in,hn) -- R5/R8-proven ----
// magg is now fp16: A-fragment loads are direct uint4 (no conversion); re-zero
// writes halve to 16B/lane-chunk.
__global__ __launch_bounds__(256, 2)
void k_gru(ushort* __restrict__ magg,
           const ushort* __restrict__ hb, const ushort* __restrict__ Bg,
           const float* __restrict__ b_ih, const float* __restrict__ b_hh,
           ushort* __restrict__ hb_out, int zero_m) {
    __shared__ __align__(16) ushort blds[256 * 128];  // 64 KB, XOR-swizzled slots
    int t = threadIdx.x;
    int wave = t >> 6, lane = t & 63, l31 = lane & 31, lhi = lane >> 5;
    #pragma unroll
    for (int call = 0; call < 16; call++) {           // 4096 slots of 16B, async
        int slot = call * 256 + t;
        int n = slot >> 4, p = slot & 15;
        int ssrc = p ^ (n & 15);
        const ushort* src = Bg + n * 128 + ssrc * 8;
        __builtin_amdgcn_global_load_lds(
            (const __attribute__((address_space(1))) void*)src,
            (__attribute__((address_space(3))) void*)&blds[(size_t)slot * 8],
            16, 0, 0);
    }
    int node0 = blockIdx.x * 128 + wave * 32;
    int m = node0 + l31;
    int mc = (m < NN) ? m : NN - 1;
    uint4 afr[8];
    const ushort* mrow = magg + (size_t)mc * 64;
    #pragma unroll
    for (int ks = 0; ks < 4; ks++) {
        afr[ks] = *(const uint4*)(mrow + ks * 16 + lhi * 8);
    }
    const ushort* hrow = hb + (size_t)mc * 64;
    #pragma unroll
    for (int ks = 4; ks < 8; ks++) {
        afr[ks] = *(const uint4*)(hrow + (ks - 4) * 16 + lhi * 8);
    }
    __syncthreads();                                  // staging + magg reads drained
    if (zero_m) {                                     // zero for next step's atomics
        uint4 zz = {0u, 0u, 0u, 0u};
        ushort* mw = magg + (size_t)mc * 64;
        #pragma unroll
        for (int ks = 0; ks < 4; ks++) {
            *(uint4*)(mw + ks * 16 + lhi * 8) = zz;
        }
    }
    #pragma unroll
    for (int ct = 0; ct < 2; ct++) {
        f32x16 aR = {0}, aZ = {0}, aI = {0}, aH = {0};
        int nR = 0   + ct * 32 + l31;
        int nZ = 64  + ct * 32 + l31;
        int nI = 128 + ct * 32 + l31;
        int nH = 192 + ct * 32 + l31;
        #pragma unroll
        for (int ks = 0; ks < 8; ks++) {
            int s = ks * 2 + lhi;
            half8 a = u4h8(afr[ks]);
            short8 bR = *(const short8*)&blds[nR * 128 + (s ^ (nR & 15)) * 8];
            short8 bZ = *(const short8*)&blds[nZ * 128 + (s ^ (nZ & 15)) * 8];
            short8 bI = *(const short8*)&blds[nI * 128 + (s ^ (nI & 15)) * 8];
            short8 bH = *(const short8*)&blds[nH * 128 + (s ^ (nH & 15)) * 8];
            aR = __builtin_amdgcn_mfma_f32_32x32x16_f16(a, __builtin_bit_cast(half8, bR), aR, 0, 0, 0);
            aZ = __builtin_amdgcn_mfma_f32_32x32x16_f16(a, __builtin_bit_cast(half8, bZ), aZ, 0, 0, 0);
            aI = __builtin_amdgcn_mfma_f32_32x32x16_f16(a, __builtin_bit_cast(half8, bI), aI, 0, 0, 0);
            aH = __builtin_amdgcn_mfma_f32_32x32x16_f16(a, __builtin_bit_cast(half8, bH), aH, 0, 0, 0);
        }
        int i = ct * 32 + l31;
        float brv = b_ih[i] + b_hh[i];
        float bzv = b_ih[64 + i] + b_hh[64 + i];
        float biv = b_ih[128 + i];
        float bhv = b_hh[128 + i];
        #pragma unroll
        for (int r = 0; r < 16; r++) {
            int row = (r & 3) + 8 * (r >> 2) + 4 * lhi;
            int node = node0 + row;
            if (node < NN) {
                float ho = h2f(hb[node * 64 + i]);
                float rg = fsigmoid(aR[r] + brv);
                float zg = fsigmoid(aZ[r] + bzv);
                float ng = ftanh(aI[r] + biv + rg * (aH[r] + bhv));
                float hv = (1.f - zg) * ng + zg * ho;
                hb_out[node * 64 + i] = f2h(hv);
            }
        }
    }
}

// ---- readout scatter: batch sorted -> run-length accumulate (fp16 state in) ----
__global__ __launch_bounds__(256)
void k_scatter_g(const ushort* __restrict__ hb, const int* __restrict__ batch,
                 float* __restrict__ g) {
    int t = threadIdx.x;
    int i = t & 63, sub = t >> 6;
    int n0 = blockIdx.x * 64 + sub * 16;
    if (n0 >= NN) return;
    float acc = 0.f;
    int curg = batch[n0];
    for (int q = 0; q < 16; q++) {
        int n = n0 + q;
        if (n >= NN) break;
        int gq = batch[n];                 // wave-uniform
        if (gq != curg) {
            atomicAdd(&g[curg * 64 + i], acc);
            acc = 0.f; curg = gq;
        }
        acc += h2f(hb[n * 64 + i]);
    }
    atomicAdd(&g[curg * 64 + i], acc);
}

__global__ __launch_bounds__(1024)
void k_readout(const float* __restrict__ g, const float* __restrict__ W1, const float* __restrict__ b1,
               const float* __restrict__ W2, const float* __restrict__ b2, float* __restrict__ out) {
    __shared__ float gs[64 * 64];
    __shared__ float ts[64 * 64];
    int t = threadIdx.x;
    for (int idx = t; idx < 4096; idx += 1024) gs[idx] = g[idx];
    __syncthreads();
    for (int idx = t; idx < 4096; idx += 1024) {
        int r = idx >> 6, c = idx & 63;
        float acc = b1[c];
        #pragma unroll 8
        for (int k = 0; k < 64; k++) acc += gs[r * 64 + k] * W1[k * 64 + c];
        ts[idx] = fmaxf(acc, 0.f);
    }
    __syncthreads();
    for (int idx = t; idx < 2048; idx += 1024) {
        int r = idx >> 5, c = idx & 31;
        float acc = b2[c];
        #pragma unroll 8
        for (int k = 0; k < 64; k++) acc += ts[r * 64 + k] * W2[k * 32 + c];
        out[idx] = acc;
    }
}

extern "C" void kernel_launch(void* const* d_in, const int* in_sizes, int n_in,
                              void* d_out, int out_size, void* d_ws, size_t ws_size,
                              hipStream_t stream) {
    const float* x     = (const float*)d_in[0];
    const int*   ei    = (const int*)  d_in[1];
    const float* ea    = (const float*)d_in[2];
    const int*   batch = (const int*)  d_in[3];
    const float* W_enc = (const float*)d_in[4];
    const float* b_enc = (const float*)d_in[5];
    const float* W_e1  = (const float*)d_in[6];
    const float* b_e1  = (const float*)d_in[7];
    const float* W_e2  = (const float*)d_in[8];
    const float* b_e2  = (const float*)d_in[9];
    const float* W_ih  = (const float*)d_in[10];
    const float* W_hh  = (const float*)d_in[11];
    const float* b_ih  = (const float*)d_in[12];
    const float* b_hh  = (const float*)d_in[13];
    const float* W_r1  = (const float*)d_in[14];
    const float* b_r1  = (const float*)d_in[15];
    const float* W_r2  = (const float*)d_in[16];
    const float* b_r2  = (const float*)d_in[17];
    float* out = (float*)d_out;

    float* ws    = (float*)d_ws;
    float* g     = ws;                        // NG*64 fp32
    ushort* magg = (ushort*)(g + NG * 64);    // NN*64 fp16 (atomic accum)
    ushort* hb   = magg + NN * 64;            // NN*64 fp16
    ushort* hb2  = hb   + NN * 64;            // NN*64 fp16
    ushort* zbT  = hb2  + NN * 64;            // 65*NE fp16 (row 64 = read-guard only)
    ushort* Wtb  = zbT  + (size_t)ZK * NE;    // 65*4096 fp16 (contiguous slabs)
    ushort* Bgru = Wtb  + ZK * 4096;          // 256*128 fp16 (R5 layout)
    ushort* Wet  = Bgru + 256 * 128;          // 64*128 fp16 (Wenc^T)

    hipLaunchKernelGGL(k_prep, dim3((PREP_S0 + PREP_S1 + PREP_S2 + 255) / 256), dim3(256), 0, stream,
                       W_e2, b_e2, W_ih, W_hh, W_enc, Wtb, Bgru, Wet);
    hipLaunchKernelGGL(k_enc_edge, dim3(NBENC + NBEDG), dim3(256), 0, stream,
                       x, Wet, b_enc, ea, W_e1, b_e1, hb, zbT, magg);

    ushort* hbc = hb; ushort* hbn = hb2;
    for (int s = 0; s < 3; s++) {
        hipLaunchKernelGGL(k_message, dim3(NBMSG), dim3(512), 0, stream,
                           zbT, hbc, ei, Wtb, magg);
        hipLaunchKernelGGL(k_gru,     dim3((NN + 127) / 128), dim3(256), 0, stream,
                           magg, hbc, Bgru, b_ih, b_hh, hbn, (s < 2) ? 1 : 0);
        ushort* tb = hbc; hbc = hbn; hbn = tb;
    }

    hipMemsetAsync(g, 0, (size_t)NG * 64 * sizeof(float), stream);
    hipLaunchKernelGGL(k_scatter_g, dim3((NN + 63) / 64), dim3(256), 0, stream, hbc, batch, g);
    hipLaunchKernelGGL(k_readout,   dim3(1), dim3(1024), 0, stream, g, W_r1, b_r1, W_r2, b_r2, out);
}